// Round 12
// baseline (498.545 us; speedup 1.0000x reference)
//
#include <hip/hip_runtime.h>
#include <hip/hip_bf16.h>
#include <math.h>

typedef __attribute__((ext_vector_type(8))) short short8;
typedef __attribute__((ext_vector_type(4))) float f32x4;
typedef __attribute__((ext_vector_type(4))) unsigned short us4;

#define GLOBAL_AS __attribute__((address_space(1)))
#define LDS_AS __attribute__((address_space(3)))

__device__ inline void g2l16(const void* g, void* l) {
    __builtin_amdgcn_global_load_lds((const GLOBAL_AS void*)g, (LDS_AS void*)l, 16, 0, 0);
}

__device__ inline unsigned short f2bf(float f) {   // RNE, matches __float2bfloat16 for finite
    unsigned int u = __float_as_uint(f);
    return (unsigned short)((u + 0x7fffu + ((u >> 16) & 1u)) >> 16);
}

// ---------------------------------------------------------------------------
// 256x128 MFMA GEMM, BK=32, counted vmcnt(3), 48 KiB LDS (r9-proven: 47us).
// 8 waves as 4M x 2N, wave tile 64x64, acc 4x4.
// Layout: [row][c2(4)] 16B slots, stored chunk = global ^ ((row>>1)&3):
//   coalesced staging (16 lines/gload-instr) + conflict-free ds_read_b128
//   (per 16-lane group all 8 bank-quartets hit 2x; pairs 512B apart = free).
// loop t: vmcnt(3) [tail 0] -> barrier -> ds+MFMA -> barrier -> stage(t+2).
// EPI: 1 = tanh -> bf16 (ldc cols)   2 = sigmoid -> fp32, cols < Nreal only
// ---------------------------------------------------------------------------
template <int EPI>
__global__ __launch_bounds__(512, 6) void mgemmB(
    const __hip_bfloat16* __restrict__ A,
    const __hip_bfloat16* __restrict__ W,
    const float* __restrict__ bias,
    void* __restrict__ outp,
    int lda, int ldb, int nT, int ldc, int Nreal)
{
    __shared__ __align__(16) __hip_bfloat16 sh[2][12288];   // 48 KiB

    const int tid  = threadIdx.x;
    const int wave = tid >> 6;
    const int lane = tid & 63;
    const int rBase = blockIdx.x * 256;
    const int cBase = blockIdx.y * 128;

    const __hip_bfloat16* Ab = A + (size_t)rBase * lda;
    const __hip_bfloat16* Wb = W + (size_t)cBase * ldb;

    const int wr = (wave >> 1) * 64;
    const int wc = (wave & 1) * 64;
    const int h  = lane >> 4;
    const int r0 = lane & 15;
    const int swz = h ^ ((r0 >> 1) & 3);

    f32x4 acc[4][4];
#pragma unroll
    for (int m = 0; m < 4; ++m)
#pragma unroll
        for (int n = 0; n < 4; ++n) acc[m][n] = (f32x4){0.f, 0.f, 0.f, 0.f};

    auto stage = [&](int bb, int t) {
        const int k0 = t * 32;
#pragma unroll
        for (int r = 0; r < 2; ++r) {
            int s2  = r * 512 + tid;
            int row = s2 >> 2;
            int cg  = (s2 & 3) ^ ((row >> 1) & 3);
            g2l16(Ab + (size_t)row * lda + k0 + cg * 8, &sh[bb][s2 * 8]);
        }
        {
            int s2  = tid;
            int row = s2 >> 2;
            int cg  = (s2 & 3) ^ ((row >> 1) & 3);
            g2l16(Wb + (size_t)row * ldb + k0 + cg * 8, &sh[bb][8192 + s2 * 8]);
        }
    };

    auto compute = [&](int bb) {
        const __hip_bfloat16* base = &sh[bb][0];
        short8 a_[4], b_[4];
#pragma unroll
        for (int m = 0; m < 4; ++m) {
            int R = wr + m * 16 + r0;
            a_[m] = *(const short8*)(base + (R * 4 + swz) * 8);
        }
#pragma unroll
        for (int n = 0; n < 4; ++n) {
            int R = wc + n * 16 + r0;
            b_[n] = *(const short8*)(base + 8192 + (R * 4 + swz) * 8);
        }
        __builtin_amdgcn_s_setprio(1);
#pragma unroll
        for (int m = 0; m < 4; ++m)
#pragma unroll
            for (int n = 0; n < 4; ++n)
                acc[m][n] = __builtin_amdgcn_mfma_f32_16x16x32_bf16(a_[m], b_[n], acc[m][n], 0, 0, 0);
        __builtin_amdgcn_s_setprio(0);
    };

    stage(0, 0);
    stage(1, 1);
    for (int t = 0; t < nT; ++t) {
        const int cur = t & 1;
        if (t + 1 < nT) asm volatile("s_waitcnt vmcnt(3)" ::: "memory");
        else            asm volatile("s_waitcnt vmcnt(0)" ::: "memory");
        __builtin_amdgcn_s_barrier();
        compute(cur);
        __builtin_amdgcn_s_barrier();
        if (t + 2 < nT) stage(cur, t + 2);
    }

    const int rq = lane >> 4;
    const int c0 = lane & 15;
#pragma unroll
    for (int m = 0; m < 4; ++m) {
#pragma unroll
        for (int n = 0; n < 4; ++n) {
            f32x4 v = acc[m][n];
            const int gc = cBase + wc + n * 16 + c0;
            const float bv = bias[gc];
#pragma unroll
            for (int j = 0; j < 4; ++j) {
                const int gr = rBase + wr + m * 16 + rq * 4 + j;
                float val = v[j] + bv;
                if (EPI == 1) {
                    ((__hip_bfloat16*)outp)[(size_t)gr * ldc + gc] = __float2bfloat16(tanhf(val));
                } else {
                    if (gc < Nreal)
                        ((float*)outp)[(size_t)gr * Nreal + gc] = 1.f / (1.f + expf(-val));
                }
            }
        }
    }
}

// ---------------------------------------------------------------------------
// 128x128 MFMA GEMM, BK=32, counted vmcnt(4), 32 KiB LDS — heads (EPI 0),
// decode (EPI 1). Same proven schedule/swizzle as mgemmB, smaller tile.
// ---------------------------------------------------------------------------
template <int EPI>
__global__ __launch_bounds__(256, 4) void mgemmC(
    const __hip_bfloat16* __restrict__ A,
    const __hip_bfloat16* __restrict__ W,
    const float* __restrict__ bias,
    void* __restrict__ outp,
    int lda, int ldb, int nT, int ldc, int Nreal)
{
    __shared__ __align__(16) __hip_bfloat16 sh[2][8192];   // 32 KiB

    const int tid  = threadIdx.x;
    const int wave = tid >> 6;
    const int lane = tid & 63;
    const int rBase = blockIdx.x * 128;
    const int cBase = blockIdx.y * 128;

    const __hip_bfloat16* Ab = A + (size_t)rBase * lda;
    const __hip_bfloat16* Wb = W + (size_t)cBase * ldb;

    const int wr = (wave >> 1) * 64;
    const int wc = (wave & 1) * 64;
    const int h  = lane >> 4;
    const int r0 = lane & 15;
    const int swz = h ^ ((r0 >> 1) & 3);

    f32x4 acc[4][4];
#pragma unroll
    for (int m = 0; m < 4; ++m)
#pragma unroll
        for (int n = 0; n < 4; ++n) acc[m][n] = (f32x4){0.f, 0.f, 0.f, 0.f};

    auto stage = [&](int bb, int t) {
        const int k0 = t * 32;
#pragma unroll
        for (int r = 0; r < 2; ++r) {
            int s2  = r * 256 + tid;
            int row = s2 >> 2;
            int cg  = (s2 & 3) ^ ((row >> 1) & 3);
            g2l16(Ab + (size_t)row * lda + k0 + cg * 8, &sh[bb][s2 * 8]);
            g2l16(Wb + (size_t)row * ldb + k0 + cg * 8, &sh[bb][4096 + s2 * 8]);
        }
    };

    auto compute = [&](int bb) {
        const __hip_bfloat16* base = &sh[bb][0];
        short8 a_[4], b_[4];
#pragma unroll
        for (int m = 0; m < 4; ++m) {
            int R = wr + m * 16 + r0;
            a_[m] = *(const short8*)(base + (R * 4 + swz) * 8);
        }
#pragma unroll
        for (int n = 0; n < 4; ++n) {
            int R = wc + n * 16 + r0;
            b_[n] = *(const short8*)(base + 4096 + (R * 4 + swz) * 8);
        }
        __builtin_amdgcn_s_setprio(1);
#pragma unroll
        for (int m = 0; m < 4; ++m)
#pragma unroll
            for (int n = 0; n < 4; ++n)
                acc[m][n] = __builtin_amdgcn_mfma_f32_16x16x32_bf16(a_[m], b_[n], acc[m][n], 0, 0, 0);
        __builtin_amdgcn_s_setprio(0);
    };

    stage(0, 0);
    stage(1, 1);
    for (int t = 0; t < nT; ++t) {
        const int cur = t & 1;
        if (t + 1 < nT) asm volatile("s_waitcnt vmcnt(4)" ::: "memory");
        else            asm volatile("s_waitcnt vmcnt(0)" ::: "memory");
        __builtin_amdgcn_s_barrier();
        compute(cur);
        __builtin_amdgcn_s_barrier();
        if (t + 2 < nT) stage(cur, t + 2);
    }

    const int rq = lane >> 4;
    const int c0 = lane & 15;
#pragma unroll
    for (int m = 0; m < 4; ++m) {
#pragma unroll
        for (int n = 0; n < 4; ++n) {
            f32x4 v = acc[m][n];
            const int gc = cBase + wc + n * 16 + c0;
            const float bv = bias[gc];
#pragma unroll
            for (int j = 0; j < 4; ++j) {
                const int gr = rBase + wr + m * 16 + rq * 4 + j;
                float val = v[j] + bv;
                if (EPI == 0) {
                    const int sel = gc >> 6, cc = gc & 63;
                    if (sel < 3) {
                        if (sel == 1) val = fminf(fmaxf(val, -4.5f), 0.f);
                        ((float*)outp)[(size_t)sel * (16384u * 64u) + (size_t)gr * 64 + cc] = val;
                    }
                } else if (EPI == 1) {
                    ((__hip_bfloat16*)outp)[(size_t)gr * ldc + gc] = __float2bfloat16(tanhf(val));
                }
            }
        }
    }
}

// ---------------------------------------------------------------------------
// prep1: [x | W_ih] [*,784] -> bf16 [17408,832]; whead pack; bhead; bho pad
// ---------------------------------------------------------------------------
__global__ void prep1(const float* __restrict__ x, const float* __restrict__ Wih,
                      const float* __restrict__ Wm, const float* __restrict__ Wlv,
                      const float* __restrict__ Wap, const float* __restrict__ bm,
                      const float* __restrict__ blv, const float* __restrict__ bap,
                      const float* __restrict__ bho_src,
                      unsigned short* __restrict__ xw,
                      unsigned short* __restrict__ whead,
                      float* __restrict__ bhead, float* __restrict__ bho)
{
    const long SEG0 = 17408L * 208, SEG1 = SEG0 + 65536, SEG2 = SEG1 + 64, SEG3 = SEG2 + 256;
    long u = (long)blockIdx.x * 256 + threadIdx.x;
    if (u < SEG0) {
        long r = u / 208;
        int  c = (int)(u - r * 208) * 4;
        us4 o = (us4){0, 0, 0, 0};
        if (c < 784) {
            const float* src = (r < 16384) ? (x + r * 784) : (Wih + (r - 16384) * 784);
            float4 v = *(const float4*)(src + c);
            o.x = f2bf(v.x); o.y = f2bf(v.y); o.z = f2bf(v.z); o.w = f2bf(v.w);
        }
        *(us4*)(xw + r * 832 + c) = o;
    } else if (u < SEG1) {
        long t = u - SEG0;
        int r = (int)(t >> 8), c = (int)(t & 255) * 4;
        us4 o = (us4){0, 0, 0, 0};
        const float* src = nullptr;
        if (r < 64)       src = Wm + (size_t)r * 1024;
        else if (r < 128) src = Wlv + (size_t)(r - 64) * 1024;
        else if (r < 192) src = Wap + (size_t)(r - 128) * 1024;
        if (src) {
            float4 v = *(const float4*)(src + c);
            o.x = f2bf(v.x); o.y = f2bf(v.y); o.z = f2bf(v.z); o.w = f2bf(v.w);
        }
        *(us4*)(whead + (size_t)r * 1024 + c) = o;
    } else if (u < SEG2) {
        int base = (int)(u - SEG1) * 4;
#pragma unroll
        for (int k = 0; k < 4; ++k) {
            int p = base + k;
            float v = 0.f;
            if (p < 64)       v = bm[p];
            else if (p < 128) v = blv[p - 64];
            else if (p < 192) v = bap[p - 128];
            bhead[p] = v;
        }
    } else if (u < SEG3) {
        int base = (int)(u - SEG2) * 4;
#pragma unroll
        for (int k = 0; k < 4; ++k) {
            int p = base + k;
            bho[p] = (p < 784) ? bho_src[p] : 0.f;
        }
    }
}

// prep2 (after encode; writes into dead xb space): whob [1024,1024], wlhb [1024,64]
__global__ void prep2(const float* __restrict__ Who, const float* __restrict__ Wlh,
                      unsigned short* __restrict__ whob, unsigned short* __restrict__ wlhb)
{
    const long SEG0 = 262144, SEG1 = SEG0 + 16384;
    long u = (long)blockIdx.x * 256 + threadIdx.x;
    if (u < SEG0) {
        int r = (int)(u >> 8), c = (int)(u & 255) * 4;
        us4 o = (us4){0, 0, 0, 0};
        if (r < 784) {
            float4 v = *(const float4*)(Who + (size_t)r * 1024 + c);
            o.x = f2bf(v.x); o.y = f2bf(v.y); o.z = f2bf(v.z); o.w = f2bf(v.w);
        }
        *(us4*)(whob + (size_t)r * 1024 + c) = o;
    } else if (u < SEG1) {
        long t = u - SEG0;
        int r = (int)(t >> 4), c = (int)(t & 15) * 4;
        float4 v = *(const float4*)(Wlh + (size_t)r * 64 + c);
        us4 o;
        o.x = f2bf(v.x); o.y = f2bf(v.y); o.z = f2bf(v.z); o.w = f2bf(v.w);
        *(us4*)(wlhb + (size_t)r * 64 + c) = o;
    }
}

// ---------------------------------------------------------------------------
// Reparameterization (closed-form rank-1; verified) + bf16 z copy
// ---------------------------------------------------------------------------
__global__ __launch_bounds__(256) void reparam_kernel(
    const float* __restrict__ mean, const float* __restrict__ logvar,
    const float* __restrict__ approx, const float* __restrict__ eps,
    float* __restrict__ z, __hip_bfloat16* __restrict__ zb, int B)
{
    const int gid  = blockIdx.x * 256 + threadIdx.x;
    const int row  = gid >> 6;
    const int lane = threadIdx.x & 63;
    if (row >= B) return;

    const size_t idx = (size_t)row * 64 + lane;
    const float m  = mean[idx];
    const float lv = logvar[idx];
    const float a  = approx[idx];
    const float ep = eps[idx];

    const float s  = expf(-lv);
    const float x1 = a * a * s;
    const float x2 = s * a * ep;

    float R = x1, S = x2;
#pragma unroll
    for (int off = 1; off < 64; off <<= 1) {
        float r2 = __shfl_down(R, off, 64);
        float s2 = __shfl_down(S, off, 64);
        if (lane + off < 64) { R += r2; S += s2; }
    }
    const float Rexc  = R - x1;
    const float Sexc  = S - x2;
    const float inv1R = 1.f / (1.f + R);
    const float dL    = sqrtf(s * (1.f + Rexc) * inv1R);
    const float bj    = -s * a * inv1R / dL;

    const float zv = m + dL * ep + bj * Sexc;
    z[idx]  = zv;
    zb[idx] = __float2bfloat16(zv);
}

// ---------------------------------------------------------------------------
extern "C" void kernel_launch(void* const* d_in, const int* in_sizes, int n_in,
                              void* d_out, int out_size, void* d_ws, size_t ws_size,
                              hipStream_t stream)
{
    const float* x    = (const float*)d_in[0];
    const float* eps  = (const float*)d_in[1];
    const float* W_ih = (const float*)d_in[2];
    const float* b_ih = (const float*)d_in[3];
    const float* W_m  = (const float*)d_in[4];
    const float* b_m  = (const float*)d_in[5];
    const float* W_lv = (const float*)d_in[6];
    const float* b_lv = (const float*)d_in[7];
    const float* W_ap = (const float*)d_in[8];
    const float* b_ap = (const float*)d_in[9];
    const float* W_lh = (const float*)d_in[10];
    const float* b_lh = (const float*)d_in[11];
    const float* W_ho = (const float*)d_in[12];
    const float* b_ho = (const float*)d_in[13];

    const int B = 16384;

    float* out    = (float*)d_out;
    float* x_mean = out;
    float* z      = out + (size_t)B * 784;
    float* mean   = z + (size_t)B * 64;
    float* logvar = mean + (size_t)B * 64;
    float* approx = logvar + (size_t)B * 64;

    // ---- workspace layout (r9-proven offsets, <= 65.3 MB) ----
    char* ws = (char*)d_ws;
    __hip_bfloat16* hb    = (__hip_bfloat16*)(ws + 0);          // [16384,1024] (reused as h2b)
    __hip_bfloat16* xb    = (__hip_bfloat16*)(ws + 33554432);   // [17408,832]: x rows then W_ih rows
    __hip_bfloat16* wihb  = (__hip_bfloat16*)(ws + 60817408);   // = xb + 16384 rows
    __hip_bfloat16* whead = (__hip_bfloat16*)(ws + 62521344);   // [256,1024]
    float*          bhead = (float*)(ws + 65273856);            // [256]
    float*          bho   = (float*)(ws + 65274880);            // [1024]
    // after encode, xb region is dead; reuse it:
    __hip_bfloat16* zb    = (__hip_bfloat16*)(ws + 33554432);   // [16384,64]
    __hip_bfloat16* whob  = (__hip_bfloat16*)(ws + 37748736);   // [1024,1024]
    __hip_bfloat16* wlhb  = (__hip_bfloat16*)(ws + 39845888);   // [1024,64]
    __hip_bfloat16* h2b   = hb;

    // ---- prep1 ----
    {
        long total = 17408L * 208 + 65536 + 64 + 256;
        prep1<<<dim3((total + 255) / 256), dim3(256), 0, stream>>>(
            x, W_ih, W_m, W_lv, W_ap, b_m, b_lv, b_ap, b_ho,
            (unsigned short*)xb, (unsigned short*)whead, bhead, bho);
    }

    // ---- encode: hidden = tanh(x @ W_ih^T + b_ih) -> bf16 [B,1024] (Kp=832, 26 tiles) ----
    mgemmB<1><<<dim3(64, 8), dim3(512), 0, stream>>>(xb, wihb, b_ih, hb, 832, 832, 26, 1024, 1024);

    // ---- prep2 (into dead xb space): whob, wlhb ----
    prep2<<<dim3((262144 + 16384 + 255) / 256), dim3(256), 0, stream>>>(
        W_ho, W_lh, (unsigned short*)whob, (unsigned short*)wlhb);

    // ---- heads: [mean|logvar|approx] = hidden @ Whead^T -> fp32 planes ----
    mgemmC<0><<<dim3(128, 2), dim3(256), 0, stream>>>(hb, whead, bhead, mean, 1024, 1024, 32, 0, 192);

    // ---- reparameterize ----
    reparam_kernel<<<dim3((B * 64) / 256), dim3(256), 0, stream>>>(mean, logvar, approx, eps, z, zb, B);

    // ---- decode: h2 = tanh(z @ W_lh^T + b_lh) -> bf16 [B,1024] (K=64, 2 tiles) ----
    mgemmC<1><<<dim3(128, 8), dim3(256), 0, stream>>>(zb, wlhb, b_lh, h2b, 64, 64, 2, 1024, 1024);

    // ---- output: x_mean = sigmoid(h2 @ W_ho^T + b_ho) -> fp32 [B,784] (Np=896, 32 tiles) ----
    mgemmB<2><<<dim3(64, 7), dim3(512), 0, stream>>>(h2b, whob, bho, x_mean, 1024, 1024, 32, 784, 784);
}

// Round 13
// 149.265 us; speedup vs baseline: 3.3400x; 3.3400x over previous
//
#include <hip/hip_runtime.h>
#include <hip/hip_bf16.h>
#include <math.h>

typedef __attribute__((ext_vector_type(8))) short short8;
typedef __attribute__((ext_vector_type(4))) float f32x4;
typedef __attribute__((ext_vector_type(4))) unsigned short us4;

#define GLOBAL_AS __attribute__((address_space(1)))
#define LDS_AS __attribute__((address_space(3)))

__device__ inline void g2l16(const void* g, void* l) {
    __builtin_amdgcn_global_load_lds((const GLOBAL_AS void*)g, (LDS_AS void*)l, 16, 0, 0);
}

__device__ inline unsigned short f2bf(float f) {   // RNE, matches __float2bfloat16 for finite
    unsigned int u = __float_as_uint(f);
    return (unsigned short)((u + 0x7fffu + ((u >> 16) & 1u)) >> 16);
}

// ---------------------------------------------------------------------------
// 256x128 MFMA GEMM, BK=32, counted vmcnt(3), 48 KiB LDS (r9-proven: 47us).
// __launch_bounds__(512,4): r12 lesson — (512,6) caps VGPR at ~85/wave and
// SPILLS the 64-reg accumulator to scratch (FETCH 25->200MB, 47->247us).
// 4 waves/EU = 2 blocks/CU is the max this register budget funds.
// 8 waves as 4M x 2N, wave tile 64x64, acc 4x4.
// Layout: [row][c2(4)] 16B slots, stored chunk = global ^ ((row>>1)&3):
//   coalesced staging (16 lines/gload-instr) + conflict-free ds_read_b128.
// loop t: vmcnt(3) [tail 0] -> barrier -> ds+MFMA -> barrier -> stage(t+2).
// EPI: 1 = tanh -> bf16 (ldc cols)   2 = sigmoid -> fp32, cols < Nreal only
// ---------------------------------------------------------------------------
template <int EPI>
__global__ __launch_bounds__(512, 4) void mgemmB(
    const __hip_bfloat16* __restrict__ A,
    const __hip_bfloat16* __restrict__ W,
    const float* __restrict__ bias,
    void* __restrict__ outp,
    int lda, int ldb, int nT, int ldc, int Nreal)
{
    __shared__ __align__(16) __hip_bfloat16 sh[2][12288];   // 48 KiB

    const int tid  = threadIdx.x;
    const int wave = tid >> 6;
    const int lane = tid & 63;
    const int rBase = blockIdx.x * 256;
    const int cBase = blockIdx.y * 128;

    const __hip_bfloat16* Ab = A + (size_t)rBase * lda;
    const __hip_bfloat16* Wb = W + (size_t)cBase * ldb;

    const int wr = (wave >> 1) * 64;
    const int wc = (wave & 1) * 64;
    const int h  = lane >> 4;
    const int r0 = lane & 15;
    const int swz = h ^ ((r0 >> 1) & 3);

    f32x4 acc[4][4];
#pragma unroll
    for (int m = 0; m < 4; ++m)
#pragma unroll
        for (int n = 0; n < 4; ++n) acc[m][n] = (f32x4){0.f, 0.f, 0.f, 0.f};

    auto stage = [&](int bb, int t) {
        const int k0 = t * 32;
#pragma unroll
        for (int r = 0; r < 2; ++r) {
            int s2  = r * 512 + tid;
            int row = s2 >> 2;
            int cg  = (s2 & 3) ^ ((row >> 1) & 3);
            g2l16(Ab + (size_t)row * lda + k0 + cg * 8, &sh[bb][s2 * 8]);
        }
        {
            int s2  = tid;
            int row = s2 >> 2;
            int cg  = (s2 & 3) ^ ((row >> 1) & 3);
            g2l16(Wb + (size_t)row * ldb + k0 + cg * 8, &sh[bb][8192 + s2 * 8]);
        }
    };

    auto compute = [&](int bb) {
        const __hip_bfloat16* base = &sh[bb][0];
        short8 a_[4], b_[4];
#pragma unroll
        for (int m = 0; m < 4; ++m) {
            int R = wr + m * 16 + r0;
            a_[m] = *(const short8*)(base + (R * 4 + swz) * 8);
        }
#pragma unroll
        for (int n = 0; n < 4; ++n) {
            int R = wc + n * 16 + r0;
            b_[n] = *(const short8*)(base + 8192 + (R * 4 + swz) * 8);
        }
        __builtin_amdgcn_s_setprio(1);
#pragma unroll
        for (int m = 0; m < 4; ++m)
#pragma unroll
            for (int n = 0; n < 4; ++n)
                acc[m][n] = __builtin_amdgcn_mfma_f32_16x16x32_bf16(a_[m], b_[n], acc[m][n], 0, 0, 0);
        __builtin_amdgcn_s_setprio(0);
    };

    stage(0, 0);
    stage(1, 1);
    for (int t = 0; t < nT; ++t) {
        const int cur = t & 1;
        if (t + 1 < nT) asm volatile("s_waitcnt vmcnt(3)" ::: "memory");
        else            asm volatile("s_waitcnt vmcnt(0)" ::: "memory");
        __builtin_amdgcn_s_barrier();
        compute(cur);
        __builtin_amdgcn_s_barrier();
        if (t + 2 < nT) stage(cur, t + 2);
    }

    const int rq = lane >> 4;
    const int c0 = lane & 15;
#pragma unroll
    for (int m = 0; m < 4; ++m) {
#pragma unroll
        for (int n = 0; n < 4; ++n) {
            f32x4 v = acc[m][n];
            const int gc = cBase + wc + n * 16 + c0;
            const float bv = bias[gc];
#pragma unroll
            for (int j = 0; j < 4; ++j) {
                const int gr = rBase + wr + m * 16 + rq * 4 + j;
                float val = v[j] + bv;
                if (EPI == 1) {
                    ((__hip_bfloat16*)outp)[(size_t)gr * ldc + gc] = __float2bfloat16(tanhf(val));
                } else {
                    if (gc < Nreal)
                        ((float*)outp)[(size_t)gr * Nreal + gc] = 1.f / (1.f + expf(-val));
                }
            }
        }
    }
}

// ---------------------------------------------------------------------------
// 128x128 MFMA GEMM, BK=32, counted vmcnt(4), 32 KiB LDS — heads (EPI 0),
// decode (EPI 1). Same proven schedule/swizzle as mgemmB, smaller tile.
// ---------------------------------------------------------------------------
template <int EPI>
__global__ __launch_bounds__(256, 4) void mgemmC(
    const __hip_bfloat16* __restrict__ A,
    const __hip_bfloat16* __restrict__ W,
    const float* __restrict__ bias,
    void* __restrict__ outp,
    int lda, int ldb, int nT, int ldc, int Nreal)
{
    __shared__ __align__(16) __hip_bfloat16 sh[2][8192];   // 32 KiB

    const int tid  = threadIdx.x;
    const int wave = tid >> 6;
    const int lane = tid & 63;
    const int rBase = blockIdx.x * 128;
    const int cBase = blockIdx.y * 128;

    const __hip_bfloat16* Ab = A + (size_t)rBase * lda;
    const __hip_bfloat16* Wb = W + (size_t)cBase * ldb;

    const int wr = (wave >> 1) * 64;
    const int wc = (wave & 1) * 64;
    const int h  = lane >> 4;
    const int r0 = lane & 15;
    const int swz = h ^ ((r0 >> 1) & 3);

    f32x4 acc[4][4];
#pragma unroll
    for (int m = 0; m < 4; ++m)
#pragma unroll
        for (int n = 0; n < 4; ++n) acc[m][n] = (f32x4){0.f, 0.f, 0.f, 0.f};

    auto stage = [&](int bb, int t) {
        const int k0 = t * 32;
#pragma unroll
        for (int r = 0; r < 2; ++r) {
            int s2  = r * 256 + tid;
            int row = s2 >> 2;
            int cg  = (s2 & 3) ^ ((row >> 1) & 3);
            g2l16(Ab + (size_t)row * lda + k0 + cg * 8, &sh[bb][s2 * 8]);
            g2l16(Wb + (size_t)row * ldb + k0 + cg * 8, &sh[bb][4096 + s2 * 8]);
        }
    };

    auto compute = [&](int bb) {
        const __hip_bfloat16* base = &sh[bb][0];
        short8 a_[4], b_[4];
#pragma unroll
        for (int m = 0; m < 4; ++m) {
            int R = wr + m * 16 + r0;
            a_[m] = *(const short8*)(base + (R * 4 + swz) * 8);
        }
#pragma unroll
        for (int n = 0; n < 4; ++n) {
            int R = wc + n * 16 + r0;
            b_[n] = *(const short8*)(base + 4096 + (R * 4 + swz) * 8);
        }
        __builtin_amdgcn_s_setprio(1);
#pragma unroll
        for (int m = 0; m < 4; ++m)
#pragma unroll
            for (int n = 0; n < 4; ++n)
                acc[m][n] = __builtin_amdgcn_mfma_f32_16x16x32_bf16(a_[m], b_[n], acc[m][n], 0, 0, 0);
        __builtin_amdgcn_s_setprio(0);
    };

    stage(0, 0);
    stage(1, 1);
    for (int t = 0; t < nT; ++t) {
        const int cur = t & 1;
        if (t + 1 < nT) asm volatile("s_waitcnt vmcnt(4)" ::: "memory");
        else            asm volatile("s_waitcnt vmcnt(0)" ::: "memory");
        __builtin_amdgcn_s_barrier();
        compute(cur);
        __builtin_amdgcn_s_barrier();
        if (t + 2 < nT) stage(cur, t + 2);
    }

    const int rq = lane >> 4;
    const int c0 = lane & 15;
#pragma unroll
    for (int m = 0; m < 4; ++m) {
#pragma unroll
        for (int n = 0; n < 4; ++n) {
            f32x4 v = acc[m][n];
            const int gc = cBase + wc + n * 16 + c0;
            const float bv = bias[gc];
#pragma unroll
            for (int j = 0; j < 4; ++j) {
                const int gr = rBase + wr + m * 16 + rq * 4 + j;
                float val = v[j] + bv;
                if (EPI == 0) {
                    const int sel = gc >> 6, cc = gc & 63;
                    if (sel < 3) {
                        if (sel == 1) val = fminf(fmaxf(val, -4.5f), 0.f);
                        ((float*)outp)[(size_t)sel * (16384u * 64u) + (size_t)gr * 64 + cc] = val;
                    }
                } else if (EPI == 1) {
                    ((__hip_bfloat16*)outp)[(size_t)gr * ldc + gc] = __float2bfloat16(tanhf(val));
                }
            }
        }
    }
}

// ---------------------------------------------------------------------------
// prep1: [x | W_ih] [*,784] -> bf16 [17408,832]; whead pack; bhead; bho pad
// ---------------------------------------------------------------------------
__global__ void prep1(const float* __restrict__ x, const float* __restrict__ Wih,
                      const float* __restrict__ Wm, const float* __restrict__ Wlv,
                      const float* __restrict__ Wap, const float* __restrict__ bm,
                      const float* __restrict__ blv, const float* __restrict__ bap,
                      const float* __restrict__ bho_src,
                      unsigned short* __restrict__ xw,
                      unsigned short* __restrict__ whead,
                      float* __restrict__ bhead, float* __restrict__ bho)
{
    const long SEG0 = 17408L * 208, SEG1 = SEG0 + 65536, SEG2 = SEG1 + 64, SEG3 = SEG2 + 256;
    long u = (long)blockIdx.x * 256 + threadIdx.x;
    if (u < SEG0) {
        long r = u / 208;
        int  c = (int)(u - r * 208) * 4;
        us4 o = (us4){0, 0, 0, 0};
        if (c < 784) {
            const float* src = (r < 16384) ? (x + r * 784) : (Wih + (r - 16384) * 784);
            float4 v = *(const float4*)(src + c);
            o.x = f2bf(v.x); o.y = f2bf(v.y); o.z = f2bf(v.z); o.w = f2bf(v.w);
        }
        *(us4*)(xw + r * 832 + c) = o;
    } else if (u < SEG1) {
        long t = u - SEG0;
        int r = (int)(t >> 8), c = (int)(t & 255) * 4;
        us4 o = (us4){0, 0, 0, 0};
        const float* src = nullptr;
        if (r < 64)       src = Wm + (size_t)r * 1024;
        else if (r < 128) src = Wlv + (size_t)(r - 64) * 1024;
        else if (r < 192) src = Wap + (size_t)(r - 128) * 1024;
        if (src) {
            float4 v = *(const float4*)(src + c);
            o.x = f2bf(v.x); o.y = f2bf(v.y); o.z = f2bf(v.z); o.w = f2bf(v.w);
        }
        *(us4*)(whead + (size_t)r * 1024 + c) = o;
    } else if (u < SEG2) {
        int base = (int)(u - SEG1) * 4;
#pragma unroll
        for (int k = 0; k < 4; ++k) {
            int p = base + k;
            float v = 0.f;
            if (p < 64)       v = bm[p];
            else if (p < 128) v = blv[p - 64];
            else if (p < 192) v = bap[p - 128];
            bhead[p] = v;
        }
    } else if (u < SEG3) {
        int base = (int)(u - SEG2) * 4;
#pragma unroll
        for (int k = 0; k < 4; ++k) {
            int p = base + k;
            bho[p] = (p < 784) ? bho_src[p] : 0.f;
        }
    }
}

// prep2 (after encode; writes into dead xb space): whob [1024,1024], wlhb [1024,64]
__global__ void prep2(const float* __restrict__ Who, const float* __restrict__ Wlh,
                      unsigned short* __restrict__ whob, unsigned short* __restrict__ wlhb)
{
    const long SEG0 = 262144, SEG1 = SEG0 + 16384;
    long u = (long)blockIdx.x * 256 + threadIdx.x;
    if (u < SEG0) {
        int r = (int)(u >> 8), c = (int)(u & 255) * 4;
        us4 o = (us4){0, 0, 0, 0};
        if (r < 784) {
            float4 v = *(const float4*)(Who + (size_t)r * 1024 + c);
            o.x = f2bf(v.x); o.y = f2bf(v.y); o.z = f2bf(v.z); o.w = f2bf(v.w);
        }
        *(us4*)(whob + (size_t)r * 1024 + c) = o;
    } else if (u < SEG1) {
        long t = u - SEG0;
        int r = (int)(t >> 4), c = (int)(t & 15) * 4;
        float4 v = *(const float4*)(Wlh + (size_t)r * 64 + c);
        us4 o;
        o.x = f2bf(v.x); o.y = f2bf(v.y); o.z = f2bf(v.z); o.w = f2bf(v.w);
        *(us4*)(wlhb + (size_t)r * 64 + c) = o;
    }
}

// ---------------------------------------------------------------------------
// Reparameterization (closed-form rank-1; verified) + bf16 z copy
// ---------------------------------------------------------------------------
__global__ __launch_bounds__(256) void reparam_kernel(
    const float* __restrict__ mean, const float* __restrict__ logvar,
    const float* __restrict__ approx, const float* __restrict__ eps,
    float* __restrict__ z, __hip_bfloat16* __restrict__ zb, int B)
{
    const int gid  = blockIdx.x * 256 + threadIdx.x;
    const int row  = gid >> 6;
    const int lane = threadIdx.x & 63;
    if (row >= B) return;

    const size_t idx = (size_t)row * 64 + lane;
    const float m  = mean[idx];
    const float lv = logvar[idx];
    const float a  = approx[idx];
    const float ep = eps[idx];

    const float s  = expf(-lv);
    const float x1 = a * a * s;
    const float x2 = s * a * ep;

    float R = x1, S = x2;
#pragma unroll
    for (int off = 1; off < 64; off <<= 1) {
        float r2 = __shfl_down(R, off, 64);
        float s2 = __shfl_down(S, off, 64);
        if (lane + off < 64) { R += r2; S += s2; }
    }
    const float Rexc  = R - x1;
    const float Sexc  = S - x2;
    const float inv1R = 1.f / (1.f + R);
    const float dL    = sqrtf(s * (1.f + Rexc) * inv1R);
    const float bj    = -s * a * inv1R / dL;

    const float zv = m + dL * ep + bj * Sexc;
    z[idx]  = zv;
    zb[idx] = __float2bfloat16(zv);
}

// ---------------------------------------------------------------------------
extern "C" void kernel_launch(void* const* d_in, const int* in_sizes, int n_in,
                              void* d_out, int out_size, void* d_ws, size_t ws_size,
                              hipStream_t stream)
{
    const float* x    = (const float*)d_in[0];
    const float* eps  = (const float*)d_in[1];
    const float* W_ih = (const float*)d_in[2];
    const float* b_ih = (const float*)d_in[3];
    const float* W_m  = (const float*)d_in[4];
    const float* b_m  = (const float*)d_in[5];
    const float* W_lv = (const float*)d_in[6];
    const float* b_lv = (const float*)d_in[7];
    const float* W_ap = (const float*)d_in[8];
    const float* b_ap = (const float*)d_in[9];
    const float* W_lh = (const float*)d_in[10];
    const float* b_lh = (const float*)d_in[11];
    const float* W_ho = (const float*)d_in[12];
    const float* b_ho = (const float*)d_in[13];

    const int B = 16384;

    float* out    = (float*)d_out;
    float* x_mean = out;
    float* z      = out + (size_t)B * 784;
    float* mean   = z + (size_t)B * 64;
    float* logvar = mean + (size_t)B * 64;
    float* approx = logvar + (size_t)B * 64;

    // ---- workspace layout (r9-proven offsets, <= 65.3 MB) ----
    char* ws = (char*)d_ws;
    __hip_bfloat16* hb    = (__hip_bfloat16*)(ws + 0);          // [16384,1024] (reused as h2b)
    __hip_bfloat16* xb    = (__hip_bfloat16*)(ws + 33554432);   // [17408,832]: x rows then W_ih rows
    __hip_bfloat16* wihb  = (__hip_bfloat16*)(ws + 60817408);   // = xb + 16384 rows
    __hip_bfloat16* whead = (__hip_bfloat16*)(ws + 62521344);   // [256,1024]
    float*          bhead = (float*)(ws + 65273856);            // [256]
    float*          bho   = (float*)(ws + 65274880);            // [1024]
    // after encode, xb region is dead; reuse it:
    __hip_bfloat16* zb    = (__hip_bfloat16*)(ws + 33554432);   // [16384,64]
    __hip_bfloat16* whob  = (__hip_bfloat16*)(ws + 37748736);   // [1024,1024]
    __hip_bfloat16* wlhb  = (__hip_bfloat16*)(ws + 39845888);   // [1024,64]
    __hip_bfloat16* h2b   = hb;

    // ---- prep1 ----
    {
        long total = 17408L * 208 + 65536 + 64 + 256;
        prep1<<<dim3((total + 255) / 256), dim3(256), 0, stream>>>(
            x, W_ih, W_m, W_lv, W_ap, b_m, b_lv, b_ap, b_ho,
            (unsigned short*)xb, (unsigned short*)whead, bhead, bho);
    }

    // ---- encode: hidden = tanh(x @ W_ih^T + b_ih) -> bf16 [B,1024] (Kp=832, 26 tiles) ----
    mgemmB<1><<<dim3(64, 8), dim3(512), 0, stream>>>(xb, wihb, b_ih, hb, 832, 832, 26, 1024, 1024);

    // ---- prep2 (into dead xb space): whob, wlhb ----
    prep2<<<dim3((262144 + 16384 + 255) / 256), dim3(256), 0, stream>>>(
        W_ho, W_lh, (unsigned short*)whob, (unsigned short*)wlhb);

    // ---- heads: [mean|logvar|approx] = hidden @ Whead^T -> fp32 planes ----
    mgemmC<0><<<dim3(128, 2), dim3(256), 0, stream>>>(hb, whead, bhead, mean, 1024, 1024, 32, 0, 192);

    // ---- reparameterize ----
    reparam_kernel<<<dim3((B * 64) / 256), dim3(256), 0, stream>>>(mean, logvar, approx, eps, z, zb, B);

    // ---- decode: h2 = tanh(z @ W_lh^T + b_lh) -> bf16 [B,1024] (K=64, 2 tiles) ----
    mgemmC<1><<<dim3(128, 8), dim3(256), 0, stream>>>(zb, wlhb, b_lh, h2b, 64, 64, 2, 1024, 1024);

    // ---- output: x_mean = sigmoid(h2 @ W_ho^T + b_ho) -> fp32 [B,784] (Np=896, 32 tiles) ----
    mgemmB<2><<<dim3(64, 7), dim3(512), 0, stream>>>(h2b, whob, bho, x_mean, 1024, 1024, 32, 784, 784);
}

// Round 14
// 144.855 us; speedup vs baseline: 3.4417x; 1.0304x over previous
//
#include <hip/hip_runtime.h>
#include <hip/hip_bf16.h>
#include <math.h>

typedef __attribute__((ext_vector_type(8))) short short8;
typedef __attribute__((ext_vector_type(4))) float f32x4;
typedef __attribute__((ext_vector_type(4))) unsigned short us4;

#define GLOBAL_AS __attribute__((address_space(1)))
#define LDS_AS __attribute__((address_space(3)))

__device__ inline void g2l16(const void* g, void* l) {
    __builtin_amdgcn_global_load_lds((const GLOBAL_AS void*)g, (LDS_AS void*)l, 16, 0, 0);
}

__device__ inline unsigned short f2bf(float f) {   // RNE, matches __float2bfloat16 for finite
    unsigned int u = __float_as_uint(f);
    return (unsigned short)((u + 0x7fffu + ((u >> 16) & 1u)) >> 16);
}

// ---------------------------------------------------------------------------
// 256x128 MFMA GEMM, BK=32, counted vmcnt(3), 48 KiB LDS (r9/r13-proven 47us).
// (512,4): r12 lesson — (512,6) caps regs ~85/wave and spills the accumulator
// (FETCH 25->200MB, 47->247us). 4 waves/EU = 2 blocks/CU is what 120 regs fund.
// Layout: [row][c2(4)] 16B slots, stored chunk = global ^ ((row>>1)&3):
//   coalesced staging (16 lines/gload-instr) + conflict-free ds_read_b128.
// loop t: vmcnt(3) [tail 0] -> barrier -> ds+MFMA -> barrier -> stage(t+2).
// EPI: 1 = tanh -> bf16 (ldc cols)   2 = sigmoid -> fp32, cols < Nreal only
// ---------------------------------------------------------------------------
template <int EPI>
__global__ __launch_bounds__(512, 4) void mgemmB(
    const __hip_bfloat16* __restrict__ A,
    const __hip_bfloat16* __restrict__ W,
    const float* __restrict__ bias,
    void* __restrict__ outp,
    int lda, int ldb, int nT, int ldc, int Nreal)
{
    __shared__ __align__(16) __hip_bfloat16 sh[2][12288];   // 48 KiB

    const int tid  = threadIdx.x;
    const int wave = tid >> 6;
    const int lane = tid & 63;
    const int rBase = blockIdx.x * 256;
    const int cBase = blockIdx.y * 128;

    const __hip_bfloat16* Ab = A + (size_t)rBase * lda;
    const __hip_bfloat16* Wb = W + (size_t)cBase * ldb;

    const int wr = (wave >> 1) * 64;
    const int wc = (wave & 1) * 64;
    const int h  = lane >> 4;
    const int r0 = lane & 15;
    const int swz = h ^ ((r0 >> 1) & 3);

    f32x4 acc[4][4];
#pragma unroll
    for (int m = 0; m < 4; ++m)
#pragma unroll
        for (int n = 0; n < 4; ++n) acc[m][n] = (f32x4){0.f, 0.f, 0.f, 0.f};

    auto stage = [&](int bb, int t) {
        const int k0 = t * 32;
#pragma unroll
        for (int r = 0; r < 2; ++r) {
            int s2  = r * 512 + tid;
            int row = s2 >> 2;
            int cg  = (s2 & 3) ^ ((row >> 1) & 3);
            g2l16(Ab + (size_t)row * lda + k0 + cg * 8, &sh[bb][s2 * 8]);
        }
        {
            int s2  = tid;
            int row = s2 >> 2;
            int cg  = (s2 & 3) ^ ((row >> 1) & 3);
            g2l16(Wb + (size_t)row * ldb + k0 + cg * 8, &sh[bb][8192 + s2 * 8]);
        }
    };

    auto compute = [&](int bb) {
        const __hip_bfloat16* base = &sh[bb][0];
        short8 a_[4], b_[4];
#pragma unroll
        for (int m = 0; m < 4; ++m) {
            int R = wr + m * 16 + r0;
            a_[m] = *(const short8*)(base + (R * 4 + swz) * 8);
        }
#pragma unroll
        for (int n = 0; n < 4; ++n) {
            int R = wc + n * 16 + r0;
            b_[n] = *(const short8*)(base + 8192 + (R * 4 + swz) * 8);
        }
        __builtin_amdgcn_s_setprio(1);
#pragma unroll
        for (int m = 0; m < 4; ++m)
#pragma unroll
            for (int n = 0; n < 4; ++n)
                acc[m][n] = __builtin_amdgcn_mfma_f32_16x16x32_bf16(a_[m], b_[n], acc[m][n], 0, 0, 0);
        __builtin_amdgcn_s_setprio(0);
    };

    stage(0, 0);
    stage(1, 1);
    for (int t = 0; t < nT; ++t) {
        const int cur = t & 1;
        if (t + 1 < nT) asm volatile("s_waitcnt vmcnt(3)" ::: "memory");
        else            asm volatile("s_waitcnt vmcnt(0)" ::: "memory");
        __builtin_amdgcn_s_barrier();
        compute(cur);
        __builtin_amdgcn_s_barrier();
        if (t + 2 < nT) stage(cur, t + 2);
    }

    const int rq = lane >> 4;
    const int c0 = lane & 15;
#pragma unroll
    for (int m = 0; m < 4; ++m) {
#pragma unroll
        for (int n = 0; n < 4; ++n) {
            f32x4 v = acc[m][n];
            const int gc = cBase + wc + n * 16 + c0;
            const float bv = bias[gc];
#pragma unroll
            for (int j = 0; j < 4; ++j) {
                const int gr = rBase + wr + m * 16 + rq * 4 + j;
                float val = v[j] + bv;
                if (EPI == 1) {
                    ((__hip_bfloat16*)outp)[(size_t)gr * ldc + gc] = __float2bfloat16(tanhf(val));
                } else {
                    if (gc < Nreal)
                        ((float*)outp)[(size_t)gr * Nreal + gc] = 1.f / (1.f + expf(-val));
                }
            }
        }
    }
}

// ---------------------------------------------------------------------------
// 128x128 MFMA GEMM, BK=32, counted vmcnt(4), 32 KiB LDS — decode (EPI 1).
// ---------------------------------------------------------------------------
template <int EPI>
__global__ __launch_bounds__(256, 4) void mgemmC(
    const __hip_bfloat16* __restrict__ A,
    const __hip_bfloat16* __restrict__ W,
    const float* __restrict__ bias,
    void* __restrict__ outp,
    int lda, int ldb, int nT, int ldc, int Nreal)
{
    __shared__ __align__(16) __hip_bfloat16 sh[2][8192];   // 32 KiB

    const int tid  = threadIdx.x;
    const int wave = tid >> 6;
    const int lane = tid & 63;
    const int rBase = blockIdx.x * 128;
    const int cBase = blockIdx.y * 128;

    const __hip_bfloat16* Ab = A + (size_t)rBase * lda;
    const __hip_bfloat16* Wb = W + (size_t)cBase * ldb;

    const int wr = (wave >> 1) * 64;
    const int wc = (wave & 1) * 64;
    const int h  = lane >> 4;
    const int r0 = lane & 15;
    const int swz = h ^ ((r0 >> 1) & 3);

    f32x4 acc[4][4];
#pragma unroll
    for (int m = 0; m < 4; ++m)
#pragma unroll
        for (int n = 0; n < 4; ++n) acc[m][n] = (f32x4){0.f, 0.f, 0.f, 0.f};

    auto stage = [&](int bb, int t) {
        const int k0 = t * 32;
#pragma unroll
        for (int r = 0; r < 2; ++r) {
            int s2  = r * 256 + tid;
            int row = s2 >> 2;
            int cg  = (s2 & 3) ^ ((row >> 1) & 3);
            g2l16(Ab + (size_t)row * lda + k0 + cg * 8, &sh[bb][s2 * 8]);
            g2l16(Wb + (size_t)row * ldb + k0 + cg * 8, &sh[bb][4096 + s2 * 8]);
        }
    };

    auto compute = [&](int bb) {
        const __hip_bfloat16* base = &sh[bb][0];
        short8 a_[4], b_[4];
#pragma unroll
        for (int m = 0; m < 4; ++m) {
            int R = wr + m * 16 + r0;
            a_[m] = *(const short8*)(base + (R * 4 + swz) * 8);
        }
#pragma unroll
        for (int n = 0; n < 4; ++n) {
            int R = wc + n * 16 + r0;
            b_[n] = *(const short8*)(base + 4096 + (R * 4 + swz) * 8);
        }
        __builtin_amdgcn_s_setprio(1);
#pragma unroll
        for (int m = 0; m < 4; ++m)
#pragma unroll
            for (int n = 0; n < 4; ++n)
                acc[m][n] = __builtin_amdgcn_mfma_f32_16x16x32_bf16(a_[m], b_[n], acc[m][n], 0, 0, 0);
        __builtin_amdgcn_s_setprio(0);
    };

    stage(0, 0);
    stage(1, 1);
    for (int t = 0; t < nT; ++t) {
        const int cur = t & 1;
        if (t + 1 < nT) asm volatile("s_waitcnt vmcnt(4)" ::: "memory");
        else            asm volatile("s_waitcnt vmcnt(0)" ::: "memory");
        __builtin_amdgcn_s_barrier();
        compute(cur);
        __builtin_amdgcn_s_barrier();
        if (t + 2 < nT) stage(cur, t + 2);
    }

    const int rq = lane >> 4;
    const int c0 = lane & 15;
#pragma unroll
    for (int m = 0; m < 4; ++m) {
#pragma unroll
        for (int n = 0; n < 4; ++n) {
            f32x4 v = acc[m][n];
            const int gc = cBase + wc + n * 16 + c0;
            const float bv = bias[gc];
#pragma unroll
            for (int j = 0; j < 4; ++j) {
                const int gr = rBase + wr + m * 16 + rq * 4 + j;
                float val = v[j] + bv;
                if (EPI == 1) {
                    ((__hip_bfloat16*)outp)[(size_t)gr * ldc + gc] = __float2bfloat16(tanhf(val));
                }
            }
        }
    }
}

// ---------------------------------------------------------------------------
// headrep: fused heads-GEMM + reparameterization. Grid 256 x 256 thr (4 waves).
// Per block: C[64x192] = hidden[64rows x 1024] @ whead[192,1024]^T, BK=64,
// 16 tiles, counted vmcnt(8); wave tile 64x48 (4 M-frags x 3 N-frags).
// LDS per buf: A[ks2][64][c2] 512 slots + B[ks2][192][c2] 1536 slots, 32KB x2.
// Swizzle identical to mgemmB (g(row)=(row>>1)&3; wnb=wave*48, 48%4==0 so
// swz=h^((r0>>1)&3) still exact). Epilogue: acc -> LDS fp32 [64][200]
// (stride 200 => banks spread, <=2-way), barrier, then per-row reparam
// (16 rows/wave, 64-lane suffix scans — r1-proven math), writing
// mean/logvar/approx/z (d_out) + zb (ws) directly. Saves reparam kernel +
// plane re-read.
// ---------------------------------------------------------------------------
__global__ __launch_bounds__(256, 2) void headrep(
    const __hip_bfloat16* __restrict__ hidden,   // [16384,1024]
    const __hip_bfloat16* __restrict__ Whead,    // [256,1024] (192 used)
    const float* __restrict__ bhead,             // [256]
    const float* __restrict__ eps,               // [16384,64]
    float* __restrict__ meanp, float* __restrict__ logvarp,
    float* __restrict__ approxp, float* __restrict__ zp,
    __hip_bfloat16* __restrict__ zb)
{
    __shared__ __align__(16) __hip_bfloat16 sh[2][16384];   // 64 KiB

    const int tid  = threadIdx.x;
    const int wave = tid >> 6;
    const int lane = tid & 63;
    const int rBase = blockIdx.x * 64;

    const __hip_bfloat16* Ab = hidden + (size_t)rBase * 1024;

    const int wnb = wave * 48;          // wave col base
    const int h  = lane >> 4;
    const int r0 = lane & 15;
    const int swz = h ^ ((r0 >> 1) & 3);

    f32x4 acc[4][3];
#pragma unroll
    for (int m = 0; m < 4; ++m)
#pragma unroll
        for (int n = 0; n < 3; ++n) acc[m][n] = (f32x4){0.f, 0.f, 0.f, 0.f};

    // stage BK=64 tile t into buf bb: per ks-half A 256 slots + B 768 slots
    auto stage = [&](int bb, int t) {
#pragma unroll
        for (int ks = 0; ks < 2; ++ks) {
            const int k0 = t * 64 + ks * 32;
            {
                int s2 = tid, row = s2 >> 2;
                int cg = (s2 & 3) ^ ((row >> 1) & 3);
                g2l16(Ab + (size_t)row * 1024 + k0 + cg * 8, &sh[bb][(ks * 256 + s2) * 8]);
            }
#pragma unroll
            for (int r = 0; r < 3; ++r) {
                int s2 = r * 256 + tid, row = s2 >> 2;
                int cg = (s2 & 3) ^ ((row >> 1) & 3);
                g2l16(Whead + (size_t)row * 1024 + k0 + cg * 8,
                      &sh[bb][(512 + ks * 768 + s2) * 8]);
            }
        }
    };

    auto compute = [&](int bb) {
#pragma unroll
        for (int ks = 0; ks < 2; ++ks) {
            const __hip_bfloat16* base = &sh[bb][0];
            short8 a_[4], b_[3];
#pragma unroll
            for (int m = 0; m < 4; ++m) {
                int R = m * 16 + r0;
                a_[m] = *(const short8*)(base + ((ks * 256) + R * 4 + swz) * 8);
            }
#pragma unroll
            for (int n = 0; n < 3; ++n) {
                int R = wnb + n * 16 + r0;
                b_[n] = *(const short8*)(base + (512 + ks * 768 + R * 4 + swz) * 8);
            }
            __builtin_amdgcn_s_setprio(1);
#pragma unroll
            for (int m = 0; m < 4; ++m)
#pragma unroll
                for (int n = 0; n < 3; ++n)
                    acc[m][n] = __builtin_amdgcn_mfma_f32_16x16x32_bf16(a_[m], b_[n], acc[m][n], 0, 0, 0);
            __builtin_amdgcn_s_setprio(0);
        }
    };

    stage(0, 0);
    stage(1, 1);
    const int nT = 16;
    for (int t = 0; t < nT; ++t) {
        const int cur = t & 1;
        if (t + 1 < nT) asm volatile("s_waitcnt vmcnt(8)" ::: "memory");
        else            asm volatile("s_waitcnt vmcnt(0)" ::: "memory");
        __builtin_amdgcn_s_barrier();
        compute(cur);
        __builtin_amdgcn_s_barrier();
        if (t + 2 < nT) stage(cur, t + 2);
    }

    // ---- epilogue 1: acc -> LDS fp32 [64][200] (staging LDS now dead) ----
    float* cs = (float*)&sh[0][0];
    const int rq = lane >> 4;
    const int c0 = lane & 15;
#pragma unroll
    for (int m = 0; m < 4; ++m)
#pragma unroll
        for (int n = 0; n < 3; ++n)
#pragma unroll
            for (int j = 0; j < 4; ++j)
                cs[(m * 16 + rq * 4 + j) * 200 + wnb + n * 16 + c0] = acc[m][n][j];
    __syncthreads();

    // ---- epilogue 2: per-row reparam (16 rows per wave) ----
    const float bm_  = bhead[lane];
    const float blv_ = bhead[64 + lane];
    const float bap_ = bhead[128 + lane];
#pragma unroll 4
    for (int r16 = 0; r16 < 16; ++r16) {
        const int row = wave * 16 + r16;
        const int gr  = rBase + row;
        const float mv = cs[row * 200 + lane] + bm_;
        float lv = cs[row * 200 + 64 + lane] + blv_;
        lv = fminf(fmaxf(lv, -4.5f), 0.f);
        const float ap = cs[row * 200 + 128 + lane] + bap_;
        const float ep = eps[(size_t)gr * 64 + lane];

        const float s  = expf(-lv);
        const float x1 = ap * ap * s;
        const float x2 = s * ap * ep;
        float R = x1, S = x2;
#pragma unroll
        for (int off = 1; off < 64; off <<= 1) {
            float r2 = __shfl_down(R, off, 64);
            float s2 = __shfl_down(S, off, 64);
            if (lane + off < 64) { R += r2; S += s2; }
        }
        const float Rexc  = R - x1;
        const float Sexc  = S - x2;
        const float inv1R = 1.f / (1.f + R);
        const float dL    = sqrtf(s * (1.f + Rexc) * inv1R);
        const float bj    = -s * ap * inv1R / dL;
        const float zv    = mv + dL * ep + bj * Sexc;

        const size_t idx = (size_t)gr * 64 + lane;
        meanp[idx]   = mv;
        logvarp[idx] = lv;
        approxp[idx] = ap;
        zp[idx]      = zv;
        zb[idx]      = __float2bfloat16(zv);
    }
}

// ---------------------------------------------------------------------------
// prep1 (all conversions, one kernel):
//  seg0: [x | W_ih] [*,784] -> bf16 slab [17408,800]
//  seg1: whead pack [256,1024]   seg2: whob [1024,1024] (rows>=784 zero)
//  seg3: wlhb [1024,64]          seg4: bhead[256]        seg5: bho[1024]
// ---------------------------------------------------------------------------
__global__ void prep1(const float* __restrict__ x, const float* __restrict__ Wih,
                      const float* __restrict__ Wm, const float* __restrict__ Wlv,
                      const float* __restrict__ Wap, const float* __restrict__ bm,
                      const float* __restrict__ blv, const float* __restrict__ bap,
                      const float* __restrict__ Who, const float* __restrict__ Wlh,
                      const float* __restrict__ bho_src,
                      unsigned short* __restrict__ slab,
                      unsigned short* __restrict__ whead,
                      unsigned short* __restrict__ whob,
                      unsigned short* __restrict__ wlhb,
                      float* __restrict__ bhead, float* __restrict__ bho)
{
    const long SEG0 = 17408L * 200;
    const long SEG1 = SEG0 + 65536;
    const long SEG2 = SEG1 + 262144;
    const long SEG3 = SEG2 + 16384;
    const long SEG4 = SEG3 + 64;
    const long SEG5 = SEG4 + 256;
    long u = (long)blockIdx.x * 256 + threadIdx.x;
    if (u < SEG0) {
        long r = u / 200;
        int  c = (int)(u - r * 200) * 4;
        us4 o = (us4){0, 0, 0, 0};
        if (c < 784) {
            const float* src = (r < 16384) ? (x + r * 784) : (Wih + (r - 16384) * 784);
            float4 v = *(const float4*)(src + c);
            o.x = f2bf(v.x); o.y = f2bf(v.y); o.z = f2bf(v.z); o.w = f2bf(v.w);
        }
        *(us4*)(slab + r * 800 + c) = o;
    } else if (u < SEG1) {
        long t = u - SEG0;
        int r = (int)(t >> 8), c = (int)(t & 255) * 4;
        us4 o = (us4){0, 0, 0, 0};
        const float* src = nullptr;
        if (r < 64)       src = Wm + (size_t)r * 1024;
        else if (r < 128) src = Wlv + (size_t)(r - 64) * 1024;
        else if (r < 192) src = Wap + (size_t)(r - 128) * 1024;
        if (src) {
            float4 v = *(const float4*)(src + c);
            o.x = f2bf(v.x); o.y = f2bf(v.y); o.z = f2bf(v.z); o.w = f2bf(v.w);
        }
        *(us4*)(whead + (size_t)r * 1024 + c) = o;
    } else if (u < SEG2) {
        long t = u - SEG1;
        int r = (int)(t >> 8), c = (int)(t & 255) * 4;
        us4 o = (us4){0, 0, 0, 0};
        if (r < 784) {
            float4 v = *(const float4*)(Who + (size_t)r * 1024 + c);
            o.x = f2bf(v.x); o.y = f2bf(v.y); o.z = f2bf(v.z); o.w = f2bf(v.w);
        }
        *(us4*)(whob + (size_t)r * 1024 + c) = o;
    } else if (u < SEG3) {
        long t = u - SEG2;
        int r = (int)(t >> 4), c = (int)(t & 15) * 4;
        float4 v = *(const float4*)(Wlh + (size_t)r * 64 + c);
        us4 o;
        o.x = f2bf(v.x); o.y = f2bf(v.y); o.z = f2bf(v.z); o.w = f2bf(v.w);
        *(us4*)(wlhb + (size_t)r * 64 + c) = o;
    } else if (u < SEG4) {
        int base = (int)(u - SEG3) * 4;
#pragma unroll
        for (int k = 0; k < 4; ++k) {
            int p = base + k;
            float v = 0.f;
            if (p < 64)       v = bm[p];
            else if (p < 128) v = blv[p - 64];
            else if (p < 192) v = bap[p - 128];
            bhead[p] = v;
        }
    } else if (u < SEG5) {
        int base = (int)(u - SEG4) * 4;
#pragma unroll
        for (int k = 0; k < 4; ++k) {
            int p = base + k;
            bho[p] = (p < 784) ? bho_src[p] : 0.f;
        }
    }
}

// ---------------------------------------------------------------------------
extern "C" void kernel_launch(void* const* d_in, const int* in_sizes, int n_in,
                              void* d_out, int out_size, void* d_ws, size_t ws_size,
                              hipStream_t stream)
{
    const float* x    = (const float*)d_in[0];
    const float* eps  = (const float*)d_in[1];
    const float* W_ih = (const float*)d_in[2];
    const float* b_ih = (const float*)d_in[3];
    const float* W_m  = (const float*)d_in[4];
    const float* b_m  = (const float*)d_in[5];
    const float* W_lv = (const float*)d_in[6];
    const float* b_lv = (const float*)d_in[7];
    const float* W_ap = (const float*)d_in[8];
    const float* b_ap = (const float*)d_in[9];
    const float* W_lh = (const float*)d_in[10];
    const float* b_lh = (const float*)d_in[11];
    const float* W_ho = (const float*)d_in[12];
    const float* b_ho = (const float*)d_in[13];

    const int B = 16384;

    float* out    = (float*)d_out;
    float* x_mean = out;
    float* z      = out + (size_t)B * 784;
    float* mean   = z + (size_t)B * 64;
    float* logvar = mean + (size_t)B * 64;
    float* approx = logvar + (size_t)B * 64;

    // ---- workspace layout (peak 64.2 MB <= proven 65.3) ----
    char* ws = (char*)d_ws;
    __hip_bfloat16* hb    = (__hip_bfloat16*)(ws + 0);          // [16384,1024] (reused as h2b)
    __hip_bfloat16* xb    = (__hip_bfloat16*)(ws + 33554432);   // slab [17408,800]: x rows, W_ih rows
    __hip_bfloat16* wihb  = (__hip_bfloat16*)(ws + 33554432 + 16384L * 800 * 2);  // = slab row 16384
    __hip_bfloat16* whead = (__hip_bfloat16*)(ws + 61407232);   // [256,1024]
    __hip_bfloat16* whob  = (__hip_bfloat16*)(ws + 61931520);   // [1024,1024]
    __hip_bfloat16* wlhb  = (__hip_bfloat16*)(ws + 64028672);   // [1024,64]
    float*          bhead = (float*)(ws + 64159744);            // [256]
    float*          bho   = (float*)(ws + 64160768);            // [1024]
    __hip_bfloat16* zb    = (__hip_bfloat16*)(ws + 33554432);   // [16384,64] in dead slab
    __hip_bfloat16* h2b   = hb;

    // ---- prep1: all conversions in one launch ----
    {
        long total = 17408L * 200 + 65536 + 262144 + 16384 + 64 + 256;
        prep1<<<dim3((total + 255) / 256), dim3(256), 0, stream>>>(
            x, W_ih, W_m, W_lv, W_ap, b_m, b_lv, b_ap, W_ho, W_lh, b_ho,
            (unsigned short*)xb, (unsigned short*)whead, (unsigned short*)whob,
            (unsigned short*)wlhb, bhead, bho);
    }

    // ---- encode: hidden = tanh(x @ W_ih^T + b_ih) -> bf16 [B,1024] (Kp=800, 25 tiles) ----
    mgemmB<1><<<dim3(64, 8), dim3(512), 0, stream>>>(xb, wihb, b_ih, hb, 800, 800, 25, 1024, 1024);

    // ---- fused heads + reparam ----
    headrep<<<dim3(256), dim3(256), 0, stream>>>(hb, whead, bhead, eps,
                                                 mean, logvar, approx, z, zb);

    // ---- decode: h2 = tanh(z @ W_lh^T + b_lh) -> bf16 [B,1024] (K=64, 2 tiles) ----
    mgemmC<1><<<dim3(128, 8), dim3(256), 0, stream>>>(zb, wlhb, b_lh, h2b, 64, 64, 2, 1024, 1024);

    // ---- output: x_mean = sigmoid(h2 @ W_ho^T + b_ho) -> fp32 [B,784] (Np=896, 32 tiles) ----
    mgemmB<2><<<dim3(64, 7), dim3(512), 0, stream>>>(h2b, whob, bho, x_mean, 1024, 1024, 32, 784, 784);
}